// Round 2
// baseline (612.620 us; speedup 1.0000x reference)
//
#include <hip/hip_runtime.h>
#include <stdint.h>

#define NB    16
#define NANCH 65536
#define NC    21
#define NCLS  20
#define NCOL  (NB * NCLS)      // 320
#define TOPK  200
#define NBINS 4096
#define CAP   256

constexpr float TH    = 0.05f;
constexpr float SCALE = (float)NBINS / 0.95f;   // bins over [0.05, 1.0]

__device__ __forceinline__ int bin_of(float s) {
  int b = (int)((s - 0.05f) * SCALE);
  return b < 0 ? 0 : (b > NBINS - 1 ? NBINS - 1 : b);
}

// ---- ws layout (bytes) ----
// scores : 0                 .. 83,886,080   (320 cols x 65536 f32)
// hist   : 83,886,080        .. +5,242,880   (320 x 4096 u32)
// sel    : 89,128,960        .. +1,280       (320 i32)
// cnt    : 89,130,240        .. +1,280       (320 u32)
// cand   : 89,131,520        .. +655,360     (320 x 256 u64)  [8-aligned]
#define OFF_SCORES 0
#define OFF_HIST   83886080LL
#define OFF_SEL    89128960LL
#define OFF_CNT    89130240LL
#define OFF_CAND   89131520LL

// ---------------- K1: softmax (classes 1..20) -> transposed scores + hist ---
__global__ __launch_bounds__(256) void softmax_hist_kernel(
    const float* __restrict__ conf, float* __restrict__ scores,
    unsigned int* __restrict__ hist) {
  int a = blockIdx.x * 256 + threadIdx.x;  // [0, NB*NANCH)
  const float* row = conf + (long long)a * NC;
  float x[NC];
#pragma unroll
  for (int c = 0; c < NC; ++c) x[c] = row[c];
  float m = x[0];
#pragma unroll
  for (int c = 1; c < NC; ++c) m = fmaxf(m, x[c]);
  float e[NC];
#pragma unroll
  for (int c = 0; c < NC; ++c) e[c] = expf(x[c] - m);
  // numpy pairwise_sum for n=21: r[j]=a[j]+a[j+8]; tree; then += a[16..20]
  float r0 = e[0] + e[8],  r1 = e[1] + e[9],  r2 = e[2] + e[10], r3 = e[3] + e[11];
  float r4 = e[4] + e[12], r5 = e[5] + e[13], r6 = e[6] + e[14], r7 = e[7] + e[15];
  float S = ((r0 + r1) + (r2 + r3)) + ((r4 + r5) + (r6 + r7));
  S += e[16]; S += e[17]; S += e[18]; S += e[19]; S += e[20];
  int b = a >> 16;              // NANCH = 65536
  int n = a & (NANCH - 1);
  long long base = ((long long)b * NCLS) * NANCH + n;
#pragma unroll
  for (int c = 1; c < NC; ++c) {
    float s = e[c] / S;                       // IEEE div, like np
    scores[base + (long long)(c - 1) * NANCH] = s;
    if (s >= TH)
      atomicAdd(&hist[(long long)(b * NCLS + (c - 1)) * NBINS + bin_of(s)], 1u);
  }
}

// ---------------- K2: per-(b,c) threshold bin from histogram ----------------
__global__ __launch_bounds__(256) void selfind_kernel(
    const unsigned int* __restrict__ hist, int* __restrict__ sel) {
  const int bc = blockIdx.x, tid = threadIdx.x;
  __shared__ unsigned int h[NBINS];
  __shared__ unsigned int part[256];
  __shared__ unsigned int suf[256];
  const unsigned int* H = hist + (long long)bc * NBINS;
  for (int i = tid; i < NBINS; i += 256) h[i] = H[i];
  __syncthreads();
  unsigned int p = 0;
#pragma unroll
  for (int i = 0; i < 16; ++i) p += h[tid * 16 + i];
  part[tid] = p;
  __syncthreads();
  if (tid == 0) {
    unsigned int run = 0;
    for (int t = 255; t >= 0; --t) { suf[t] = run; run += part[t]; }
    if (run < TOPK) sel[bc] = -1;            // fewer than 200 scores >= TH
  }
  __syncthreads();
  unsigned int above = suf[tid];
  if (above < TOPK && above + part[tid] >= TOPK) {   // exactly one owner
    unsigned int cum = above; int sb = tid * 16;
    for (int i = 15; i >= 0; --i) {
      unsigned int c = h[tid * 16 + i];
      if (cum + c >= TOPK) { sb = tid * 16 + i; break; }
      cum += c;
    }
    sel[bc] = sb;
  }
}

// ---------------- K3: parallel collect (8 blocks per column, float4) --------
__global__ __launch_bounds__(256) void collect_kernel(
    const float4* __restrict__ scores4, const int* __restrict__ sel,
    unsigned int* __restrict__ cnt, unsigned long long* __restrict__ cand) {
  const int blk = blockIdx.x;
  const int bc = blk >> 3, slice = blk & 7, tid = threadIdx.x;
  const int s0 = sel[bc];
  const float4* col = scores4 + (long long)bc * (NANCH / 4) + slice * (8192 / 4);
#pragma unroll
  for (int it = 0; it < 8; ++it) {
    float4 v = col[it * 256 + tid];
    int base_i = slice * 8192 + (it * 256 + tid) * 4;
    float vs[4] = {v.x, v.y, v.z, v.w};
#pragma unroll
    for (int k = 0; k < 4; ++k) {
      float s = vs[k];
      bool take = (s >= TH) && (s0 < 0 || bin_of(s) >= s0);
      if (take) {
        unsigned int pos = atomicAdd(&cnt[bc], 1u);
        if (pos < CAP) {
          unsigned int key = __float_as_uint(s) | 0x80000000u;  // s > 0
          cand[bc * CAP + pos] =
              ((unsigned long long)(key ^ 0xFFFFFFFFu) << 32) |
              (unsigned long long)(unsigned int)(base_i + k);
        }
      }
    }
  }
}

// ---------------- K4: sort (score desc, idx asc) + decode + NMS + output ----
__global__ __launch_bounds__(256) void sortnms_kernel(
    const unsigned long long* __restrict__ candg,
    const unsigned int* __restrict__ cnt, const float* __restrict__ loc,
    const float* __restrict__ anchors, float* __restrict__ out) {
  const int bc = blockIdx.x;
  const int b  = bc / NCLS;
  const int tid = threadIdx.x;

  __shared__ unsigned long long cand[CAP];
  __shared__ float bx[TOPK][4];
  __shared__ float barea[TOPK];
  __shared__ float bscore[TOPK];
  __shared__ unsigned long long adj[TOPK][4];
  __shared__ unsigned char keepf[TOPK];

  int ncand = (int)cnt[bc]; if (ncand > CAP) ncand = CAP;
  cand[tid] = (tid < ncand) ? candg[bc * CAP + tid] : ~0ULL;
  __syncthreads();

  // bitonic sort 256 u64 ascending = (score desc, idx asc)
  for (int k = 2; k <= CAP; k <<= 1) {
    for (int j = k >> 1; j > 0; j >>= 1) {
      int partner = tid ^ j;
      unsigned long long mine = cand[tid];
      unsigned long long theirs = cand[partner];
      bool dirUp = ((tid & k) == 0);
      bool keepMin = (tid < partner) == dirUp;
      unsigned long long v = ((mine < theirs) == keepMin) ? mine : theirs;
      __syncthreads();
      cand[tid] = v;
      __syncthreads();
    }
  }
  const int nsel = (ncand < TOPK) ? ncand : TOPK;

  // gather + decode (exact reference op order)
  if (tid < TOPK) {
    if (tid < nsel) {
      unsigned long long sk = cand[tid];
      unsigned int key = (unsigned int)(sk >> 32) ^ 0xFFFFFFFFu;
      float s = __uint_as_float(key ^ 0x80000000u);
      int idx = (int)(unsigned int)(sk & 0xFFFFFFFFu);
      float4 anc = ((const float4*)anchors)[idx];
      float4 l   = ((const float4*)loc)[(long long)b * NANCH + idx];
      float cx = anc.x + (l.x * 0.1f) * anc.z;
      float cy = anc.y + (l.y * 0.1f) * anc.w;
      float w  = anc.z * expf(l.z * 0.2f);
      float h  = anc.w * expf(l.w * 0.2f);
      float x1 = cx - 0.5f * w, y1 = cy - 0.5f * h;
      float x2 = cx + 0.5f * w, y2 = cy + 0.5f * h;
      bx[tid][0] = x1; bx[tid][1] = y1; bx[tid][2] = x2; bx[tid][3] = y2;
      barea[tid] = fmaxf(x2 - x1, 0.0f) * fmaxf(y2 - y1, 0.0f);
      bscore[tid] = s;
    } else {
      bx[tid][0] = bx[tid][1] = bx[tid][2] = bx[tid][3] = 0.0f;
      barea[tid] = 0.0f; bscore[tid] = 0.0f;
    }
  }
  __syncthreads();

  // IoU adjacency bitmask (row t: bit j set iff IoU(t,j) > 0.5)
  if (tid < TOPK) {
    float ax1 = bx[tid][0], ay1 = bx[tid][1], ax2 = bx[tid][2], ay2 = bx[tid][3];
    float aar = barea[tid];
    for (int w = 0; w < 4; ++w) {
      unsigned long long mword = 0;
      int lim = (w < 3) ? 64 : (TOPK - 192);
      for (int jj = 0; jj < lim; ++jj) {
        int j = (w << 6) + jj;
        float ltx = fmaxf(ax1, bx[j][0]);
        float lty = fmaxf(ay1, bx[j][1]);
        float rbx = fminf(ax2, bx[j][2]);
        float rby = fminf(ay2, bx[j][3]);
        float iw = fmaxf(rbx - ltx, 0.0f);
        float ih = fmaxf(rby - lty, 0.0f);
        float inter = iw * ih;
        float uni = aar + barea[j] - inter;
        float iou = inter / fmaxf(uni, 1e-9f);
        if (iou > 0.5f) mword |= (1ULL << jj);
      }
      adj[tid][w] = mword;
    }
  }
  __syncthreads();

  // serial greedy NMS with bitsets (thread 0)
  if (tid == 0) {
    unsigned long long s0 = 0, s1 = 0, s2 = 0, s3 = 0;
    for (int i = 0; i < 64; ++i) {
      bool kept = (i < nsel) && !((s0 >> i) & 1ULL);
      keepf[i] = kept ? 1 : 0;
      if (kept) { s0 |= adj[i][0]; s1 |= adj[i][1]; s2 |= adj[i][2]; s3 |= adj[i][3]; }
    }
    for (int i = 64; i < 128; ++i) {
      bool kept = (i < nsel) && !((s1 >> (i - 64)) & 1ULL);
      keepf[i] = kept ? 1 : 0;
      if (kept) { s0 |= adj[i][0]; s1 |= adj[i][1]; s2 |= adj[i][2]; s3 |= adj[i][3]; }
    }
    for (int i = 128; i < 192; ++i) {
      bool kept = (i < nsel) && !((s2 >> (i - 128)) & 1ULL);
      keepf[i] = kept ? 1 : 0;
      if (kept) { s0 |= adj[i][0]; s1 |= adj[i][1]; s2 |= adj[i][2]; s3 |= adj[i][3]; }
    }
    for (int i = 192; i < TOPK; ++i) {
      bool kept = (i < nsel) && !((s3 >> (i - 192)) & 1ULL);
      keepf[i] = kept ? 1 : 0;
      if (kept) { s0 |= adj[i][0]; s1 |= adj[i][1]; s2 |= adj[i][2]; s3 |= adj[i][3]; }
    }
  }
  __syncthreads();

  // output: (B, 20, 200, 5)
  if (tid < TOPK) {
    float* o = out + ((long long)bc * TOPK + tid) * 5;
    bool k = keepf[tid] != 0;
    o[0] = k ? bx[tid][0] : 0.0f;
    o[1] = k ? bx[tid][1] : 0.0f;
    o[2] = k ? bx[tid][2] : 0.0f;
    o[3] = k ? bx[tid][3] : 0.0f;
    o[4] = k ? bscore[tid] : 0.0f;
  }
}

extern "C" void kernel_launch(void* const* d_in, const int* in_sizes, int n_in,
                              void* d_out, int out_size, void* d_ws, size_t ws_size,
                              hipStream_t stream) {
  const float* conf    = (const float*)d_in[0];
  const float* loc     = (const float*)d_in[1];
  const float* anchors = (const float*)d_in[2];
  float* out = (float*)d_out;

  char* ws = (char*)d_ws;
  float*              scores = (float*)(ws + OFF_SCORES);
  unsigned int*       hist   = (unsigned int*)(ws + OFF_HIST);
  int*                sel    = (int*)(ws + OFF_SEL);
  unsigned int*       cnt    = (unsigned int*)(ws + OFF_CNT);
  unsigned long long* cand   = (unsigned long long*)(ws + OFF_CAND);

  // zero hist + sel + cnt (contiguous region) each call — deterministic replay
  hipMemsetAsync(ws + OFF_HIST, 0, (OFF_CAND - OFF_HIST), stream);

  softmax_hist_kernel<<<(NB * NANCH) / 256, 256, 0, stream>>>(conf, scores, hist);
  selfind_kernel<<<NCOL, 256, 0, stream>>>(hist, sel);
  collect_kernel<<<NCOL * 8, 256, 0, stream>>>((const float4*)scores, sel, cnt, cand);
  sortnms_kernel<<<NCOL, 256, 0, stream>>>(cand, cnt, loc, anchors, out);
}

// Round 3
// 110.712 us; speedup vs baseline: 5.5334x; 5.5334x over previous
//
#include <hip/hip_runtime.h>
#include <stdint.h>

#define NB     16
#define NANCH  65536
#define NC     21
#define NCLS   20
#define NCOL   (NB * NCLS)     // 320
#define TOPK   200
#define NBINS  2048
#define CAP    256
#define CAPCOL 4096

constexpr float TH      = 0.05f;
constexpr float TPRE    = 0.15f;                  // pre-filter threshold
constexpr float SCALE15 = (float)NBINS / 0.85f;   // bins over [0.15, 1.0]
constexpr float SCALE05 = (float)NBINS / 0.95f;   // fallback bins [0.05, 1.0]

__device__ __forceinline__ int bin15(float s) {
  int b = (int)((s - 0.15f) * SCALE15);
  return b < 0 ? 0 : (b > NBINS - 1 ? NBINS - 1 : b);
}
__device__ __forceinline__ int bin05(float s) {
  int b = (int)((s - 0.05f) * SCALE05);
  return b < 0 ? 0 : (b > NBINS - 1 ? NBINS - 1 : b);
}

// exact softmax pipeline shared by K1 and the K3 fallback (numpy pairwise sum)
__device__ __forceinline__ void softmax_row(const float* __restrict__ conf,
                                            long long a, float* e, float& S) {
  const float* row = conf + a * NC;
  float x[NC];
#pragma unroll
  for (int c = 0; c < NC; ++c) x[c] = row[c];
  float m = x[0];
#pragma unroll
  for (int c = 1; c < NC; ++c) m = fmaxf(m, x[c]);
#pragma unroll
  for (int c = 0; c < NC; ++c) e[c] = expf(x[c] - m);
  float r0 = e[0] + e[8],  r1 = e[1] + e[9],  r2 = e[2] + e[10], r3 = e[3] + e[11];
  float r4 = e[4] + e[12], r5 = e[5] + e[13], r6 = e[6] + e[14], r7 = e[7] + e[15];
  S = ((r0 + r1) + (r2 + r3)) + ((r4 + r5) + (r6 + r7));
  S += e[16]; S += e[17]; S += e[18]; S += e[19]; S += e[20];
}

// ---------------- K1: softmax + direct candidate collection -----------------
__global__ __launch_bounds__(256) void softmax_collect_kernel(
    const float* __restrict__ conf,
    unsigned int* __restrict__ cnt, unsigned long long* __restrict__ cand) {
  const int tid = threadIdx.x;
  const int a = blockIdx.x * 256 + tid;
  const int b = a >> 16;              // uniform per block (65536/256 exact)
  const int n = a & (NANCH - 1);
  float e[NC], S;
  softmax_row(conf, (long long)a, e, S);
  float sc[NCLS];
  unsigned int takemask = 0;
#pragma unroll
  for (int c = 0; c < NCLS; ++c) {
    sc[c] = e[c + 1] / S;             // IEEE div, like np
    if (sc[c] >= TPRE) takemask |= (1u << c);
  }

  __shared__ unsigned int wcnt[4][NCLS];
  __shared__ unsigned int wbase[4][NCLS];
  const int wave = tid >> 6, lane = tid & 63;
#pragma unroll
  for (int c = 0; c < NCLS; ++c) {
    unsigned long long m = __ballot((takemask >> c) & 1);
    if (lane == 0) wcnt[wave][c] = (unsigned int)__popcll(m);
  }
  __syncthreads();
  if (tid < NCLS) {
    const int c = tid;
    unsigned int t0 = wcnt[0][c], t1 = wcnt[1][c], t2 = wcnt[2][c], t3 = wcnt[3][c];
    unsigned int tot = t0 + t1 + t2 + t3;
    unsigned int base = tot ? atomicAdd(&cnt[b * NCLS + c], tot) : 0u;
    wbase[0][c] = base;
    wbase[1][c] = base + t0;
    wbase[2][c] = base + t0 + t1;
    wbase[3][c] = base + t0 + t1 + t2;
  }
  __syncthreads();
#pragma unroll
  for (int c = 0; c < NCLS; ++c) {
    bool take = (takemask >> c) & 1;
    unsigned long long m = __ballot(take);
    if (take) {
      unsigned int off = wbase[wave][c] +
                         (unsigned int)__popcll(m & ((1ULL << lane) - 1));
      if (off < CAPCOL) {
        unsigned int key = __float_as_uint(sc[c]) | 0x80000000u;  // s > 0
        cand[(long long)(b * NCLS + c) * CAPCOL + off] =
            ((unsigned long long)(key ^ 0xFFFFFFFFu) << 32) |
            (unsigned long long)(unsigned int)n;
      }
    }
  }
}

// ---------------- in-block cut-bin finder (hist already populated) ----------
__device__ __forceinline__ int find_sel(unsigned int* hist, unsigned int* part,
                                        unsigned int* suf, int* s_sel, int tid) {
  unsigned int p = 0;
#pragma unroll
  for (int i = 0; i < NBINS / 256; ++i) p += hist[tid * (NBINS / 256) + i];
  part[tid] = p;
  __syncthreads();
  if (tid == 0) {
    unsigned int run = 0;
    for (int t = 255; t >= 0; --t) { suf[t] = run; run += part[t]; }
    *s_sel = -1;                      // stays -1 iff total < TOPK (take all)
  }
  __syncthreads();
  unsigned int above = suf[tid];
  if (above < TOPK && above + part[tid] >= TOPK) {   // exactly one owner
    unsigned int cum = above; int sb = tid * (NBINS / 256);
    for (int i = NBINS / 256 - 1; i >= 0; --i) {
      unsigned int c = hist[tid * (NBINS / 256) + i];
      if (cum + c >= TOPK) { sb = tid * (NBINS / 256) + i; break; }
      cum += c;
    }
    *s_sel = sb;
  }
  __syncthreads();
  return *s_sel;
}

// ---------------- K3: per-column select + sort + decode + NMS + output ------
__global__ __launch_bounds__(256) void topk_nms_kernel(
    const unsigned long long* __restrict__ candg,
    const unsigned int* __restrict__ cnt,
    const float* __restrict__ conf, const float* __restrict__ loc,
    const float* __restrict__ anchors, float* __restrict__ out) {
  const int bc = blockIdx.x;
  const int b  = bc / NCLS;
  const int cls = bc % NCLS;          // conf class cls+1
  const int tid = threadIdx.x;

  __shared__ unsigned int hist[NBINS];
  __shared__ unsigned int part[256], suf[256];
  __shared__ int s_sel, s_n;
  __shared__ unsigned long long cand[CAP];
  __shared__ float bx[TOPK][4];
  __shared__ float barea[TOPK];
  __shared__ float bscore[TOPK];
  __shared__ unsigned long long adj[TOPK][4];
  __shared__ unsigned char keepf[TOPK];

  int nc = (int)cnt[bc];
  const bool fast = (nc >= TOPK && nc <= CAPCOL);
  for (int i = tid; i < NBINS; i += 256) hist[i] = 0;
  if (tid == 0) s_n = 0;
  __syncthreads();

  const unsigned long long* cg = candg + (long long)bc * CAPCOL;
  if (fast) {
    for (int i = tid; i < nc; i += 256) {
      unsigned int key = (unsigned int)(cg[i] >> 32) ^ 0xFFFFFFFFu;
      float s = __uint_as_float(key ^ 0x80000000u);
      atomicAdd(&hist[bin15(s)], 1u);
    }
    __syncthreads();
    int sel = find_sel(hist, part, suf, &s_sel, tid);   // >=0 since nc>=200
    for (int i = tid; i < nc; i += 256) {
      unsigned long long k64 = cg[i];
      unsigned int key = (unsigned int)(k64 >> 32) ^ 0xFFFFFFFFu;
      float s = __uint_as_float(key ^ 0x80000000u);
      if (bin15(s) >= sel) {
        int pos = atomicAdd(&s_n, 1);
        if (pos < CAP) cand[pos] = k64;
      }
    }
  } else {
    // fallback: full-column recompute from conf, bins over [0.05, 1]
    for (int n = tid; n < NANCH; n += 256) {
      float e[NC], S;
      softmax_row(conf, (long long)b * NANCH + n, e, S);
      float s = e[cls + 1] / S;
      if (s >= TH) atomicAdd(&hist[bin05(s)], 1u);
    }
    __syncthreads();
    int sel = find_sel(hist, part, suf, &s_sel, tid);
    for (int n = tid; n < NANCH; n += 256) {
      float e[NC], S;
      softmax_row(conf, (long long)b * NANCH + n, e, S);
      float s = e[cls + 1] / S;
      if (s >= TH && (sel < 0 || bin05(s) >= sel)) {
        int pos = atomicAdd(&s_n, 1);
        if (pos < CAP) {
          unsigned int key = __float_as_uint(s) | 0x80000000u;
          cand[pos] = ((unsigned long long)(key ^ 0xFFFFFFFFu) << 32) |
                      (unsigned long long)(unsigned int)n;
        }
      }
    }
  }
  __syncthreads();
  int ncand = s_n; if (ncand > CAP) ncand = CAP;
  for (int i = tid; i < CAP; i += 256) if (i >= ncand) cand[i] = ~0ULL;
  __syncthreads();

  // bitonic sort 256 u64 ascending = (score desc, idx asc) — lax.top_k ties
  for (int k = 2; k <= CAP; k <<= 1) {
    for (int j = k >> 1; j > 0; j >>= 1) {
      int partner = tid ^ j;
      unsigned long long mine = cand[tid];
      unsigned long long theirs = cand[partner];
      bool dirUp = ((tid & k) == 0);
      bool keepMin = (tid < partner) == dirUp;
      unsigned long long v = ((mine < theirs) == keepMin) ? mine : theirs;
      __syncthreads();
      cand[tid] = v;
      __syncthreads();
    }
  }
  const int nsel = (ncand < TOPK) ? ncand : TOPK;

  // gather + decode (exact reference op order)
  if (tid < TOPK) {
    if (tid < nsel) {
      unsigned long long sk = cand[tid];
      unsigned int key = (unsigned int)(sk >> 32) ^ 0xFFFFFFFFu;
      float s = __uint_as_float(key ^ 0x80000000u);
      int idx = (int)(unsigned int)(sk & 0xFFFFFFFFu);
      float4 anc = ((const float4*)anchors)[idx];
      float4 l   = ((const float4*)loc)[(long long)b * NANCH + idx];
      float cx = anc.x + (l.x * 0.1f) * anc.z;
      float cy = anc.y + (l.y * 0.1f) * anc.w;
      float w  = anc.z * expf(l.z * 0.2f);
      float h  = anc.w * expf(l.w * 0.2f);
      float x1 = cx - 0.5f * w, y1 = cy - 0.5f * h;
      float x2 = cx + 0.5f * w, y2 = cy + 0.5f * h;
      bx[tid][0] = x1; bx[tid][1] = y1; bx[tid][2] = x2; bx[tid][3] = y2;
      barea[tid] = fmaxf(x2 - x1, 0.0f) * fmaxf(y2 - y1, 0.0f);
      bscore[tid] = s;
    } else {
      bx[tid][0] = bx[tid][1] = bx[tid][2] = bx[tid][3] = 0.0f;
      barea[tid] = 0.0f; bscore[tid] = 0.0f;
    }
  }
  __syncthreads();

  // IoU adjacency bitmask (row t: bit j set iff IoU(t,j) > 0.5)
  if (tid < TOPK) {
    float ax1 = bx[tid][0], ay1 = bx[tid][1], ax2 = bx[tid][2], ay2 = bx[tid][3];
    float aar = barea[tid];
    for (int w = 0; w < 4; ++w) {
      unsigned long long mword = 0;
      int lim = (w < 3) ? 64 : (TOPK - 192);
      for (int jj = 0; jj < lim; ++jj) {
        int j = (w << 6) + jj;
        float ltx = fmaxf(ax1, bx[j][0]);
        float lty = fmaxf(ay1, bx[j][1]);
        float rbx = fminf(ax2, bx[j][2]);
        float rby = fminf(ay2, bx[j][3]);
        float iw = fmaxf(rbx - ltx, 0.0f);
        float ih = fmaxf(rby - lty, 0.0f);
        float inter = iw * ih;
        float uni = aar + barea[j] - inter;
        float iou = inter / fmaxf(uni, 1e-9f);
        if (iou > 0.5f) mword |= (1ULL << jj);
      }
      adj[tid][w] = mword;
    }
  }
  __syncthreads();

  // serial greedy NMS with bitsets (thread 0)
  if (tid == 0) {
    unsigned long long s0 = 0, s1 = 0, s2 = 0, s3 = 0;
    for (int i = 0; i < 64; ++i) {
      bool kept = (i < nsel) && !((s0 >> i) & 1ULL);
      keepf[i] = kept ? 1 : 0;
      if (kept) { s0 |= adj[i][0]; s1 |= adj[i][1]; s2 |= adj[i][2]; s3 |= adj[i][3]; }
    }
    for (int i = 64; i < 128; ++i) {
      bool kept = (i < nsel) && !((s1 >> (i - 64)) & 1ULL);
      keepf[i] = kept ? 1 : 0;
      if (kept) { s0 |= adj[i][0]; s1 |= adj[i][1]; s2 |= adj[i][2]; s3 |= adj[i][3]; }
    }
    for (int i = 128; i < 192; ++i) {
      bool kept = (i < nsel) && !((s2 >> (i - 128)) & 1ULL);
      keepf[i] = kept ? 1 : 0;
      if (kept) { s0 |= adj[i][0]; s1 |= adj[i][1]; s2 |= adj[i][2]; s3 |= adj[i][3]; }
    }
    for (int i = 192; i < TOPK; ++i) {
      bool kept = (i < nsel) && !((s3 >> (i - 192)) & 1ULL);
      keepf[i] = kept ? 1 : 0;
      if (kept) { s0 |= adj[i][0]; s1 |= adj[i][1]; s2 |= adj[i][2]; s3 |= adj[i][3]; }
    }
  }
  __syncthreads();

  // output: (B, 20, 200, 5)
  if (tid < TOPK) {
    float* o = out + ((long long)bc * TOPK + tid) * 5;
    bool k = keepf[tid] != 0;
    o[0] = k ? bx[tid][0] : 0.0f;
    o[1] = k ? bx[tid][1] : 0.0f;
    o[2] = k ? bx[tid][2] : 0.0f;
    o[3] = k ? bx[tid][3] : 0.0f;
    o[4] = k ? bscore[tid] : 0.0f;
  }
}

extern "C" void kernel_launch(void* const* d_in, const int* in_sizes, int n_in,
                              void* d_out, int out_size, void* d_ws, size_t ws_size,
                              hipStream_t stream) {
  const float* conf    = (const float*)d_in[0];
  const float* loc     = (const float*)d_in[1];
  const float* anchors = (const float*)d_in[2];
  float* out = (float*)d_out;

  // ws layout: cand 320*4096*8 = 10,485,760 B ; cnt 320*4 = 1,280 B
  char* ws = (char*)d_ws;
  unsigned long long* cand = (unsigned long long*)ws;
  unsigned int*       cnt  = (unsigned int*)(ws + 10485760);

  hipMemsetAsync(ws + 10485760, 0, 1280, stream);   // zero cnt each call
  softmax_collect_kernel<<<(NB * NANCH) / 256, 256, 0, stream>>>(conf, cnt, cand);
  topk_nms_kernel<<<NCOL, 256, 0, stream>>>(cand, cnt, conf, loc, anchors, out);
}

// Round 4
// 108.579 us; speedup vs baseline: 5.6422x; 1.0197x over previous
//
#include <hip/hip_runtime.h>
#include <stdint.h>

#define NB     16
#define NANCH  65536
#define NC     21
#define NCLS   20
#define NCOL   (NB * NCLS)     // 320
#define TOPK   200
#define NBINS  2048
#define CAP    256
#define CAPCOL 4096

constexpr float TH      = 0.05f;
constexpr float TPRE    = 0.15f;                  // pre-filter threshold
constexpr float SCALE15 = (float)NBINS / 0.85f;   // bins over [0.15, 1.0]
constexpr float SCALE05 = (float)NBINS / 0.95f;   // fallback bins [0.05, 1.0]

__device__ __forceinline__ int bin15(float s) {
  int b = (int)((s - 0.15f) * SCALE15);
  return b < 0 ? 0 : (b > NBINS - 1 ? NBINS - 1 : b);
}
__device__ __forceinline__ int bin05(float s) {
  int b = (int)((s - 0.05f) * SCALE05);
  return b < 0 ? 0 : (b > NBINS - 1 ? NBINS - 1 : b);
}

__device__ __forceinline__ unsigned long long shflx64(unsigned long long v, int m) {
  unsigned int lo = (unsigned int)v, hi = (unsigned int)(v >> 32);
  lo = __shfl_xor(lo, m);
  hi = __shfl_xor(hi, m);
  return ((unsigned long long)hi << 32) | lo;
}

// exact softmax tail shared by K1 and the K3 fallback (numpy pairwise sum)
__device__ __forceinline__ void softmax_tail(const float* x, float* e, float& S) {
  float m = x[0];
#pragma unroll
  for (int c = 1; c < NC; ++c) m = fmaxf(m, x[c]);
#pragma unroll
  for (int c = 0; c < NC; ++c) e[c] = expf(x[c] - m);
  float r0 = e[0] + e[8],  r1 = e[1] + e[9],  r2 = e[2] + e[10], r3 = e[3] + e[11];
  float r4 = e[4] + e[12], r5 = e[5] + e[13], r6 = e[6] + e[14], r7 = e[7] + e[15];
  S = ((r0 + r1) + (r2 + r3)) + ((r4 + r5) + (r6 + r7));
  S += e[16]; S += e[17]; S += e[18]; S += e[19]; S += e[20];
}

// ---------------- K1: coalesced LDS-staged softmax + candidate collection ---
__global__ __launch_bounds__(256) void softmax_collect_kernel(
    const float* __restrict__ conf,
    unsigned int* __restrict__ cnt, unsigned long long* __restrict__ cand) {
  const int tid = threadIdx.x;
  __shared__ float ld[256 * NC];          // 21504 B, rows at odd stride 21
  const float4* src = (const float4*)conf + (long long)blockIdx.x * 1344;
  float4* dst4 = (float4*)ld;
#pragma unroll
  for (int i = 0; i < 5; ++i) dst4[tid + i * 256] = src[tid + i * 256];
  if (tid < 64) dst4[tid + 1280] = src[tid + 1280];
  __syncthreads();

  const int a = blockIdx.x * 256 + tid;
  const int b = a >> 16;
  const int n = a & (NANCH - 1);
  float x[NC];
#pragma unroll
  for (int c = 0; c < NC; ++c) x[c] = ld[tid * NC + c];
  float e[NC], S;
  softmax_tail(x, e, S);
  float sc[NCLS];
  unsigned int takemask = 0;
#pragma unroll
  for (int c = 0; c < NCLS; ++c) {
    sc[c] = e[c + 1] / S;                 // IEEE div, like np
    if (sc[c] >= TPRE) takemask |= (1u << c);
  }

  __shared__ unsigned int wcnt[4][NCLS];
  __shared__ unsigned int wbase[4][NCLS];
  const int wave = tid >> 6, lane = tid & 63;
#pragma unroll
  for (int c = 0; c < NCLS; ++c) {
    unsigned long long m = __ballot((takemask >> c) & 1);
    if (lane == 0) wcnt[wave][c] = (unsigned int)__popcll(m);
  }
  __syncthreads();
  if (tid < NCLS) {
    const int c = tid;
    unsigned int t0 = wcnt[0][c], t1 = wcnt[1][c], t2 = wcnt[2][c], t3 = wcnt[3][c];
    unsigned int tot = t0 + t1 + t2 + t3;
    unsigned int base = tot ? atomicAdd(&cnt[b * NCLS + c], tot) : 0u;
    wbase[0][c] = base;
    wbase[1][c] = base + t0;
    wbase[2][c] = base + t0 + t1;
    wbase[3][c] = base + t0 + t1 + t2;
  }
  __syncthreads();
#pragma unroll
  for (int c = 0; c < NCLS; ++c) {
    bool take = (takemask >> c) & 1;
    unsigned long long m = __ballot(take);
    if (take) {
      unsigned int off = wbase[wave][c] +
                         (unsigned int)__popcll(m & ((1ULL << lane) - 1));
      if (off < CAPCOL) {
        unsigned int key = __float_as_uint(sc[c]) | 0x80000000u;  // s > 0
        cand[(long long)(b * NCLS + c) * CAPCOL + off] =
            ((unsigned long long)(key ^ 0xFFFFFFFFu) << 32) |
            (unsigned long long)(unsigned int)n;
      }
    }
  }
}

// ---------------- wave-0 parallel cut-bin finder (hist in LDS) --------------
// part[t] = sum(hist[8t..8t+7]); suffix-scan 64 groups of 4 parts via shfl.
__device__ __forceinline__ int find_sel(unsigned int* hist, unsigned int* part,
                                        int* s_sel, int tid) {
  unsigned int p = 0;
#pragma unroll
  for (int i = 0; i < 8; ++i) p += hist[tid * 8 + i];
  part[tid] = p;
  if (tid == 0) *s_sel = -1;
  __syncthreads();
  if (tid < 64) {
    unsigned int p4 = part[tid * 4] + part[tid * 4 + 1] +
                      part[tid * 4 + 2] + part[tid * 4 + 3];
    unsigned int sfx = p4;                 // inclusive suffix over 64 groups
#pragma unroll
    for (int off = 1; off < 64; off <<= 1) {
      unsigned int o = __shfl_down(sfx, off);
      if (tid + off < 64) sfx += o;
    }
    unsigned int above = sfx - p4;         // strictly-above-group count
    if (above < TOPK && sfx >= TOPK) {     // exactly one owner (if total>=200)
      unsigned int cum = above; int sel = tid * 32; bool found = false;
      for (int q = 3; q >= 0 && !found; --q) {
        unsigned int pc = part[tid * 4 + q];
        if (cum + pc >= TOPK) {
          for (int i = 7; i >= 0; --i) {
            unsigned int c = hist[(tid * 4 + q) * 8 + i];
            if (cum + c >= TOPK) { sel = (tid * 4 + q) * 8 + i; found = true; break; }
            cum += c;
          }
        } else cum += pc;
      }
      *s_sel = sel;
    }
  }
  __syncthreads();
  return *s_sel;
}

// ---------------- K3: per-column select + sort + decode + NMS + output ------
__global__ __launch_bounds__(256) void topk_nms_kernel(
    const unsigned long long* __restrict__ candg,
    const unsigned int* __restrict__ cnt,
    const float* __restrict__ conf, const float* __restrict__ loc,
    const float* __restrict__ anchors, float* __restrict__ out) {
  const int bc = blockIdx.x;
  const int b  = bc / NCLS;
  const int cls = bc % NCLS;
  const int tid = threadIdx.x;

  __shared__ unsigned long long cg_lds[CAPCOL];   // 32 KB
  __shared__ unsigned int hist[NBINS];
  __shared__ unsigned int part[256];
  __shared__ int s_sel, s_n;
  __shared__ unsigned long long cand[CAP];
  __shared__ float bx[TOPK][5];                   // x1,y1,x2,y2,score; stride 5
  __shared__ float barea[TOPK];
  __shared__ unsigned long long adj[TOPK][4];
  __shared__ unsigned char keepf[TOPK];

  int nc = (int)cnt[bc];
  const bool fast = (nc >= TOPK && nc <= CAPCOL);
  for (int i = tid; i < NBINS; i += 256) hist[i] = 0;
  if (tid == 0) s_n = 0;
  __syncthreads();

  if (fast) {
    const unsigned long long* cg = candg + (long long)bc * CAPCOL;
    for (int i = tid; i < nc; i += 256) {         // single global pass
      unsigned long long k64 = cg[i];
      cg_lds[i] = k64;
      unsigned int key = (unsigned int)(k64 >> 32) ^ 0xFFFFFFFFu;
      float s = __uint_as_float(key ^ 0x80000000u);
      atomicAdd(&hist[bin15(s)], 1u);
    }
    __syncthreads();
    int sel = find_sel(hist, part, &s_sel, tid);  // >=0 since nc>=200
    for (int i = tid; i < nc; i += 256) {
      unsigned long long k64 = cg_lds[i];
      unsigned int key = (unsigned int)(k64 >> 32) ^ 0xFFFFFFFFu;
      float s = __uint_as_float(key ^ 0x80000000u);
      if (bin15(s) >= sel) {
        int pos = atomicAdd(&s_n, 1);
        if (pos < CAP) cand[pos] = k64;
      }
    }
  } else {
    // fallback: full-column recompute from conf, bins over [0.05, 1]
    for (int n = tid; n < NANCH; n += 256) {
      const float* row = conf + ((long long)b * NANCH + n) * NC;
      float x[NC], e[NC], S;
#pragma unroll
      for (int c = 0; c < NC; ++c) x[c] = row[c];
      softmax_tail(x, e, S);
      float s = e[cls + 1] / S;
      if (s >= TH) atomicAdd(&hist[bin05(s)], 1u);
    }
    __syncthreads();
    int sel = find_sel(hist, part, &s_sel, tid);
    for (int n = tid; n < NANCH; n += 256) {
      const float* row = conf + ((long long)b * NANCH + n) * NC;
      float x[NC], e[NC], S;
#pragma unroll
      for (int c = 0; c < NC; ++c) x[c] = row[c];
      softmax_tail(x, e, S);
      float s = e[cls + 1] / S;
      if (s >= TH && (sel < 0 || bin05(s) >= sel)) {
        int pos = atomicAdd(&s_n, 1);
        if (pos < CAP) {
          unsigned int key = __float_as_uint(s) | 0x80000000u;
          cand[pos] = ((unsigned long long)(key ^ 0xFFFFFFFFu) << 32) |
                      (unsigned long long)(unsigned int)n;
        }
      }
    }
  }
  __syncthreads();
  int ncand = s_n; if (ncand > CAP) ncand = CAP;

  // hybrid bitonic sort: register element, shfl_xor for j<=32, LDS for j>=64.
  // ascending u64 = (score desc, idx asc) — exact lax.top_k tie semantics.
  unsigned long long v = (tid < ncand) ? cand[tid] : ~0ULL;
  for (int k = 2; k <= CAP; k <<= 1) {
    const bool up = ((tid & k) == 0);
    for (int j = k >> 1; j >= 64; j >>= 1) {
      cand[tid] = v;
      __syncthreads();
      unsigned long long o = cand[tid ^ j];
      bool keepMin = (((tid & j) == 0) == up);
      v = ((v < o) == keepMin) ? v : o;
      __syncthreads();
    }
    for (int j = (k >> 1) < 32 ? (k >> 1) : 32; j >= 1; j >>= 1) {
      unsigned long long o = shflx64(v, j);
      bool keepMin = (((tid & j) == 0) == up);
      v = ((v < o) == keepMin) ? v : o;
    }
  }
  const int nsel = (ncand < TOPK) ? ncand : TOPK;

  // gather + decode (exact reference op order); thread tid holds rank tid
  if (tid < TOPK) {
    if (tid < nsel) {
      unsigned int key = (unsigned int)(v >> 32) ^ 0xFFFFFFFFu;
      float s = __uint_as_float(key ^ 0x80000000u);
      int idx = (int)(unsigned int)(v & 0xFFFFFFFFu);
      float4 anc = ((const float4*)anchors)[idx];
      float4 l   = ((const float4*)loc)[(long long)b * NANCH + idx];
      float cx = anc.x + (l.x * 0.1f) * anc.z;
      float cy = anc.y + (l.y * 0.1f) * anc.w;
      float w  = anc.z * expf(l.z * 0.2f);
      float h  = anc.w * expf(l.w * 0.2f);
      float x1 = cx - 0.5f * w, y1 = cy - 0.5f * h;
      float x2 = cx + 0.5f * w, y2 = cy + 0.5f * h;
      bx[tid][0] = x1; bx[tid][1] = y1; bx[tid][2] = x2; bx[tid][3] = y2;
      bx[tid][4] = s;
      barea[tid] = fmaxf(x2 - x1, 0.0f) * fmaxf(y2 - y1, 0.0f);
    } else {
      bx[tid][0] = bx[tid][1] = bx[tid][2] = bx[tid][3] = bx[tid][4] = 0.0f;
      barea[tid] = 0.0f;
    }
  }
  __syncthreads();

  // IoU adjacency bitmask (row t: bit j set iff IoU(t,j) > 0.5)
  if (tid < TOPK) {
    float ax1 = bx[tid][0], ay1 = bx[tid][1], ax2 = bx[tid][2], ay2 = bx[tid][3];
    float aar = barea[tid];
    for (int w = 0; w < 4; ++w) {
      unsigned long long mword = 0;
      int lim = (w < 3) ? 64 : (TOPK - 192);
      for (int jj = 0; jj < lim; ++jj) {
        int j = (w << 6) + jj;
        float ltx = fmaxf(ax1, bx[j][0]);
        float lty = fmaxf(ay1, bx[j][1]);
        float rbx = fminf(ax2, bx[j][2]);
        float rby = fminf(ay2, bx[j][3]);
        float iw = fmaxf(rbx - ltx, 0.0f);
        float ih = fmaxf(rby - lty, 0.0f);
        float inter = iw * ih;
        float uni = aar + barea[j] - inter;
        float iou = inter / fmaxf(uni, 1e-9f);
        if (iou > 0.5f) mword |= (1ULL << jj);
      }
      adj[tid][w] = mword;
    }
  }
  __syncthreads();

  // serial greedy NMS, loads hoisted out of the conditional for pipelining
  if (tid == 0) {
    unsigned long long s0 = 0, s1 = 0, s2 = 0, s3 = 0;
    for (int i = 0; i < 64; ++i) {
      unsigned long long m0 = adj[i][0], m1 = adj[i][1],
                         m2 = adj[i][2], m3 = adj[i][3];
      bool kept = (i < nsel) && !((s0 >> i) & 1ULL);
      keepf[i] = kept ? 1 : 0;
      if (kept) { s0 |= m0; s1 |= m1; s2 |= m2; s3 |= m3; }
    }
    for (int i = 64; i < 128; ++i) {
      unsigned long long m0 = adj[i][0], m1 = adj[i][1],
                         m2 = adj[i][2], m3 = adj[i][3];
      bool kept = (i < nsel) && !((s1 >> (i - 64)) & 1ULL);
      keepf[i] = kept ? 1 : 0;
      if (kept) { s0 |= m0; s1 |= m1; s2 |= m2; s3 |= m3; }
    }
    for (int i = 128; i < 192; ++i) {
      unsigned long long m0 = adj[i][0], m1 = adj[i][1],
                         m2 = adj[i][2], m3 = adj[i][3];
      bool kept = (i < nsel) && !((s2 >> (i - 128)) & 1ULL);
      keepf[i] = kept ? 1 : 0;
      if (kept) { s0 |= m0; s1 |= m1; s2 |= m2; s3 |= m3; }
    }
    for (int i = 192; i < TOPK; ++i) {
      unsigned long long m0 = adj[i][0], m1 = adj[i][1],
                         m2 = adj[i][2], m3 = adj[i][3];
      bool kept = (i < nsel) && !((s3 >> (i - 192)) & 1ULL);
      keepf[i] = kept ? 1 : 0;
      if (kept) { s0 |= m0; s1 |= m1; s2 |= m2; s3 |= m3; }
    }
  }
  __syncthreads();

  // output: (B, 20, 200, 5)
  if (tid < TOPK) {
    float* o = out + ((long long)bc * TOPK + tid) * 5;
    bool k = keepf[tid] != 0;
    o[0] = k ? bx[tid][0] : 0.0f;
    o[1] = k ? bx[tid][1] : 0.0f;
    o[2] = k ? bx[tid][2] : 0.0f;
    o[3] = k ? bx[tid][3] : 0.0f;
    o[4] = k ? bx[tid][4] : 0.0f;
  }
}

extern "C" void kernel_launch(void* const* d_in, const int* in_sizes, int n_in,
                              void* d_out, int out_size, void* d_ws, size_t ws_size,
                              hipStream_t stream) {
  const float* conf    = (const float*)d_in[0];
  const float* loc     = (const float*)d_in[1];
  const float* anchors = (const float*)d_in[2];
  float* out = (float*)d_out;

  // ws layout: cand 320*4096*8 = 10,485,760 B ; cnt 320*4 = 1,280 B
  char* ws = (char*)d_ws;
  unsigned long long* cand = (unsigned long long*)ws;
  unsigned int*       cnt  = (unsigned int*)(ws + 10485760);

  hipMemsetAsync(ws + 10485760, 0, 1280, stream);   // zero cnt each call
  softmax_collect_kernel<<<(NB * NANCH) / 256, 256, 0, stream>>>(conf, cnt, cand);
  topk_nms_kernel<<<NCOL, 256, 0, stream>>>(cand, cnt, conf, loc, anchors, out);
}